// Round 3
// baseline (107.866 us; speedup 1.0000x reference)
//
#include <hip/hip_runtime.h>
#include <hip/hip_bf16.h>

typedef unsigned short u16;
typedef unsigned int u32;
typedef unsigned char u8;
typedef int i32x8 __attribute__((ext_vector_type(8)));
typedef float f32x4 __attribute__((ext_vector_type(4)));

#define NSPK 1024
#define NUTT 20
#define DEMB 512
#define NROW (NSPK * NUTT)   // 20480

// pack 8 fp32 -> 8 fp8 e4m3 bytes (HW cvt, gfx950 OCP format — same format MFMA eats)
__device__ __forceinline__ uint2 pk_fp8x8(float a, float b, float c, float d,
                                          float e, float f, float g, float h) {
    int lo = __builtin_amdgcn_cvt_pk_fp8_f32(a, b, 0, 0);
    lo = __builtin_amdgcn_cvt_pk_fp8_f32(c, d, lo, 1);
    int hi = __builtin_amdgcn_cvt_pk_fp8_f32(e, f, 0, 0);
    hi = __builtin_amdgcn_cvt_pk_fp8_f32(g, h, hi, 1);
    return make_uint2((u32)lo, (u32)hi);
}

// ---------------------------------------------------------------------------
// Fused prep (R6-validated, unchanged): one block per speaker; wave wv owns
// rows 5wv..5wv+4, lane owns dims 8l..8l+7. Emits FP8 e_n rows (A), FP8 c_n
// (Bc), fp32 diag/csd. Zeroes out.
// ---------------------------------------------------------------------------
__global__ __launch_bounds__(256) void prep_f(const float* __restrict__ E,
                                              u8* __restrict__ A,
                                              u8* __restrict__ Bc,
                                              float* __restrict__ diag,
                                              float* __restrict__ csd,
                                              float* __restrict__ out) {
    __shared__ float sbuf[4][DEMB];
    const int t = threadIdx.x, lane = t & 63, wv = t >> 6;
    const int n = blockIdx.x;
    const float* Eb = E + (size_t)n * (NUTT * DEMB) + (size_t)(wv * 5) * DEMB + lane * 8;

    float4 e0[5], e1[5];
    float4 p0 = {0, 0, 0, 0}, p1 = {0, 0, 0, 0};
#pragma unroll
    for (int i = 0; i < 5; ++i) {
        e0[i] = *(const float4*)(Eb + (size_t)i * DEMB);
        e1[i] = *(const float4*)(Eb + (size_t)i * DEMB + 4);
        p0.x += e0[i].x; p0.y += e0[i].y; p0.z += e0[i].z; p0.w += e0[i].w;
        p1.x += e1[i].x; p1.y += e1[i].y; p1.z += e1[i].z; p1.w += e1[i].w;
    }
    *(float4*)(&sbuf[wv][lane * 8])     = p0;
    *(float4*)(&sbuf[wv][lane * 8 + 4]) = p1;
    __syncthreads();

    float4 s0 = {0, 0, 0, 0}, s1 = {0, 0, 0, 0};
#pragma unroll
    for (int k = 0; k < 4; ++k) {
        float4 a = *(const float4*)(&sbuf[k][lane * 8]);
        float4 b = *(const float4*)(&sbuf[k][lane * 8 + 4]);
        s0.x += a.x; s0.y += a.y; s0.z += a.z; s0.w += a.w;
        s1.x += b.x; s1.y += b.y; s1.z += b.z; s1.w += b.w;
    }

    float ls = s0.x*s0.x + s0.y*s0.y + s0.z*s0.z + s0.w*s0.w
             + s1.x*s1.x + s1.y*s1.y + s1.z*s1.z + s1.w*s1.w;
#pragma unroll
    for (int o = 32; o; o >>= 1) ls += __shfl_xor(ls, o);
    const float ss = ls;                                       // ||s||^2
    const float rc = 1.0f / fmaxf(sqrtf(ss) * 0.05f, 1e-8f);   // 1/max(||c||,eps)
    const float g  = rc * 0.05f;                               // rc/20

    ((uint2*)(Bc + (size_t)n * DEMB))[lane] =
        pk_fp8x8(s0.x * g, s0.y * g, s0.z * g, s0.w * g,
                 s1.x * g, s1.y * g, s1.z * g, s1.w * g);

#pragma unroll
    for (int i = 0; i < 5; ++i) {
        float ee = e0[i].x*e0[i].x + e0[i].y*e0[i].y + e0[i].z*e0[i].z + e0[i].w*e0[i].w
                 + e1[i].x*e1[i].x + e1[i].y*e1[i].y + e1[i].z*e1[i].z + e1[i].w*e1[i].w;
        float es = e0[i].x*s0.x + e0[i].y*s0.y + e0[i].z*s0.z + e0[i].w*s0.w
                 + e1[i].x*s1.x + e1[i].y*s1.y + e1[i].z*s1.z + e1[i].w*s1.w;
#pragma unroll
        for (int o = 32; o; o >>= 1) { ee += __shfl_xor(ee, o); es += __shfl_xor(es, o); }

        const float rne = 1.0f / fmaxf(sqrtf(ee), 1e-8f);
        const float pxx = ss - 2.f * es + ee;                  // ||s-e||^2
        const float dg  = (es - ee) * rne / fmaxf(sqrtf(pxx), 1.9e-7f);

        const int r = n * NUTT + wv * 5 + i;
        ((uint2*)(A + (size_t)r * DEMB))[lane] =
            pk_fp8x8(e0[i].x * rne, e0[i].y * rne, e0[i].z * rne, e0[i].w * rne,
                     e1[i].x * rne, e1[i].y * rne, e1[i].z * rne, e1[i].w * rne);
        if (lane == 0) {
            diag[r] = dg;
            csd[r]  = es * g * rne;
        }
    }

    if (n == 0 && t == 0) out[0] = 0.f;
}

// ---------------------------------------------------------------------------
// R10: fully-fused GEMM + finalize. Grid 256 = 1 block/CU (exact round, zero
// imbalance). Block owns 80 rows x ALL 1024 cols:
//  - A-tile 80x512 fp8 staged to LDS once, then held ENTIRELY in registers
//    (20 frags x 8 VGPR = 160; legal at 1 wave/SIMD via launch_bounds(256,1)).
//  - B streamed as 32 pipelined 16KB stages (tileN-major, kt-minor), LDS
//    double-buffer, counted vmcnt(4) (R9-validated wait discipline).
//  - Row-sums complete in-block -> finalize fused; rs16 buffer, its traffic,
//    and the 3rd dispatch deleted. Per-tileN epilogue keeps per-lane partial
//    exp-sums in regs (no per-tileN shuffles); one 16-lane reduce at the end.
// Traffic: A-panels read ONCE (10 MB, was 80 MB L3); B is L2-resident
// broadcast (512 KB/XCD). R5 lesson: no __threadfence anywhere.
// ---------------------------------------------------------------------------
__device__ __forceinline__ void async_copy16(const void* g, void* l) {
    __builtin_amdgcn_global_load_lds(
        (const __attribute__((address_space(1))) void*)g,
        (__attribute__((address_space(3))) void*)l, 16, 0, 0);
}

__global__ __launch_bounds__(256, 1) void gemm_fin(const u8* __restrict__ A,
                                                   const u8* __restrict__ Bc,
                                                   const float* __restrict__ wp,
                                                   const float* __restrict__ bp,
                                                   const float* __restrict__ diag,
                                                   const float* __restrict__ csd,
                                                   float* __restrict__ out) {
    __shared__ u8 As[80 * DEMB];      // 40 KB, staged once
    __shared__ u8 Bs[2][128 * 128];   // 2x16 KB double buffer
    __shared__ float red[4][80];
    __shared__ float s_red[4];
    const int t = threadIdx.x, lane = t & 63, wv = t >> 6;
    const int ml = lane & 15, q = lane >> 4;
    const int blk = blockIdx.x;       // rows 80*blk .. 80*blk+79
    const u8* Ag = A + (size_t)blk * 80 * DEMB;

    // w/b first, then drain: if these compile to VMEM they must not perturb
    // the counted-vmcnt bookkeeping below.
    const float w = *wp, bb = *bp;
    asm volatile("s_waitcnt vmcnt(0) lgkmcnt(0)" ::: "memory");

    // B staging source offsets: chunk c = t+256j -> N-row r=c>>3, k-group
    // (c&7)^(r&7) (XOR slot swizzle; roundtrip identity with the frag reads).
    int boff[4];
#pragma unroll
    for (int j = 0; j < 4; ++j) {
        const int c = t + 256 * j;
        const int r = c >> 3, kg = (c & 7) ^ (r & 7);
        boff[j] = r * DEMB + kg * 16;
    }

    auto stageB = [&](int tileN, int kt, u8* buf) {
#pragma unroll
        for (int j = 0; j < 4; ++j)
            async_copy16(Bc + (size_t)tileN * (128 * DEMB) + kt * 128 + boff[j],
                         buf + t * 16 + j * 4096);
    };

    // ---- prologue: A (10 instrs/wave) + B stage0 + B stage1 ----
#pragma unroll
    for (int jj = 0; jj < 10; ++jj) {
        const int c = t + 256 * jj;
        const int r = c >> 5, sl = c & 31;     // 32 16B-slots per 512B row
        async_copy16(Ag + (size_t)r * DEMB + ((sl ^ (r & 31)) << 4),
                     As + t * 16 + jj * 4096);
    }
    stageB(0, 0, Bs[0]);
    stageB(0, 1, Bs[1]);
    asm volatile("s_waitcnt vmcnt(4)" ::: "memory");   // A + stage0 landed
    __builtin_amdgcn_sched_barrier(0);
    __builtin_amdgcn_s_barrier();
    __builtin_amdgcn_sched_barrier(0);

    // ---- A-tile -> registers (one time). frag m: rows m*16+ml; lane covers
    // K bytes [kt*128 + q*32, +32). XOR slot swizzle: 2-way bank = free. ----
    i32x8 a[5][4];
#pragma unroll
    for (int m = 0; m < 5; ++m) {
        const int r = m * 16 + ml;
#pragma unroll
        for (int kt = 0; kt < 4; ++kt) {
            const int sl0 = (kt * 8 + 2 * q)     ^ (r & 31);
            const int sl1 = (kt * 8 + 2 * q + 1) ^ (r & 31);
            uint4 x = *(const uint4*)(As + r * DEMB + (sl0 << 4));
            uint4 y = *(const uint4*)(As + r * DEMB + (sl1 << 4));
            a[m][kt] = (i32x8){(int)x.x, (int)x.y, (int)x.z, (int)x.w,
                               (int)y.x, (int)y.y, (int)y.z, (int)y.w};
        }
    }
    asm volatile("s_waitcnt lgkmcnt(0)" ::: "memory");
    __builtin_amdgcn_sched_barrier(0);

    f32x4 acc[5][2], rowpart[5];
#pragma unroll
    for (int m = 0; m < 5; ++m) {
        acc[m][0] = (f32x4){0.f, 0.f, 0.f, 0.f};
        acc[m][1] = (f32x4){0.f, 0.f, 0.f, 0.f};
        rowpart[m] = (f32x4){0.f, 0.f, 0.f, 0.f};
    }

    // B fragment read offsets: wave covers cols wv*32 + nf*16 + ml.
    int bo0[2], bo1[2];
#pragma unroll
    for (int nf = 0; nf < 2; ++nf) {
        const int c = wv * 32 + nf * 16 + ml;
        bo0[nf] = c * 128 + (((2 * q)     ^ (c & 7)) << 4);
        bo1[nf] = c * 128 + (((2 * q + 1) ^ (c & 7)) << 4);
    }

    // ---- 32-stage pipelined stream: stage s = (tileN, kt), buf = kt&1 ----
    for (int tileN = 0; tileN < 8; ++tileN) {
#pragma unroll
        for (int kt = 0; kt < 4; ++kt) {
            const u8* bufc = Bs[kt & 1];
            i32x8 bf[2];
#pragma unroll
            for (int nf = 0; nf < 2; ++nf) {
                uint4 x = *(const uint4*)(bufc + bo0[nf]);
                uint4 y = *(const uint4*)(bufc + bo1[nf]);
                bf[nf] = (i32x8){(int)x.x, (int)x.y, (int)x.z, (int)x.w,
                                 (int)y.x, (int)y.y, (int)y.z, (int)y.w};
            }
            asm volatile("s_waitcnt lgkmcnt(0)" ::: "memory");   // rule #18
            __builtin_amdgcn_sched_barrier(0);
#pragma unroll
            for (int m = 0; m < 5; ++m)
#pragma unroll
                for (int nf = 0; nf < 2; ++nf)
                    acc[m][nf] = __builtin_amdgcn_mfma_scale_f32_16x16x128_f8f6f4(
                        a[m][kt], bf[nf], acc[m][nf], 0, 0,
                        0, 0x7F7F7F7F, 0, 0x7F7F7F7F);

            // WAR barrier: all waves done reading buf (lgkm already 0) before
            // stage s+2 overwrites it.
            __builtin_amdgcn_sched_barrier(0);
            __builtin_amdgcn_s_barrier();
            __builtin_amdgcn_sched_barrier(0);

            // issue stage s+2 into the buffer just freed (guard: s+2 < 32)
            if (kt < 2 || tileN < 7)
                stageB(tileN + (kt >= 2), (kt + 2) & 3, (u8*)Bs[kt & 1]);

            // per-tileN epilogue: per-lane partial exp row-sums (VALU only,
            // overlaps the in-flight loads). No shuffles here.
            if (kt == 3) {
#pragma unroll
                for (int m = 0; m < 5; ++m) {
#pragma unroll
                    for (int r = 0; r < 4; ++r)
                        rowpart[m][r] += __expf(fmaf(w, acc[m][0][r] + 1e-6f, bb))
                                       + __expf(fmaf(w, acc[m][1][r] + 1e-6f, bb));
                    acc[m][0] = (f32x4){0.f, 0.f, 0.f, 0.f};
                    acc[m][1] = (f32x4){0.f, 0.f, 0.f, 0.f};
                }
            }

            // wait for stage s+1 (counted; only the stream tail drains to 0)
            if (kt == 2) {
                if (tileN == 7) { asm volatile("s_waitcnt vmcnt(0)" ::: "memory"); }
                else           { asm volatile("s_waitcnt vmcnt(4)" ::: "memory"); }
                __builtin_amdgcn_sched_barrier(0);
                __builtin_amdgcn_s_barrier();
                __builtin_amdgcn_sched_barrier(0);
            } else if (kt == 3) {
                if (tileN < 7) {
                    asm volatile("s_waitcnt vmcnt(4)" ::: "memory");
                    __builtin_amdgcn_sched_barrier(0);
                    __builtin_amdgcn_s_barrier();
                    __builtin_amdgcn_sched_barrier(0);
                }
            } else {
                asm volatile("s_waitcnt vmcnt(4)" ::: "memory");
                __builtin_amdgcn_sched_barrier(0);
                __builtin_amdgcn_s_barrier();
                __builtin_amdgcn_sched_barrier(0);
            }
        }
    }

    // ---- final: one 16-lane reduce of rowpart, cross-wave via LDS ----
#pragma unroll
    for (int m = 0; m < 5; ++m)
#pragma unroll
        for (int o = 1; o < 16; o <<= 1) {
            rowpart[m][0] += __shfl_xor(rowpart[m][0], o);
            rowpart[m][1] += __shfl_xor(rowpart[m][1], o);
            rowpart[m][2] += __shfl_xor(rowpart[m][2], o);
            rowpart[m][3] += __shfl_xor(rowpart[m][3], o);
        }
    if (ml == 0) {
#pragma unroll
        for (int m = 0; m < 5; ++m)
#pragma unroll
            for (int r = 0; r < 4; ++r)
                red[wv][m * 16 + q * 4 + r] = rowpart[m][r];   // C row = q*4+reg
    }
    __syncthreads();

    float term = 0.f;
    if (t < 80) {
        const float rsum = red[0][t] + red[1][t] + red[2][t] + red[3][t];
        const int row = blk * 80 + t;
        const float pos = fmaf(w, diag[row] + 1e-6f, bb);
        const float S = rsum - __expf(fmaf(w, csd[row] + 1e-6f, bb)) + __expf(pos);
        term = __logf(S + 1e-6f) - pos;
    }
#pragma unroll
    for (int o = 32; o; o >>= 1) term += __shfl_xor(term, o);
    if (lane == 0) s_red[wv] = term;
    __syncthreads();
    if (t == 0) atomicAdd(out, s_red[0] + s_red[1] + s_red[2] + s_red[3]);
}

extern "C" void kernel_launch(void* const* d_in, const int* in_sizes, int n_in,
                              void* d_out, int out_size, void* d_ws, size_t ws_size,
                              hipStream_t stream) {
    const float* E = (const float*)d_in[0];
    const float* wp = (const float*)d_in[1];
    const float* bp = (const float*)d_in[2];
    float* out = (float*)d_out;

    char* ws = (char*)d_ws;
    u8* A      = (u8*)(ws);                        // 20480*512   = 10,485,760 B
    u8* Bc     = (u8*)(ws + 10485760);             //  1024*512   =     524,288 B
    float* dg  = (float*)(ws + 11010048);          // 20480*4     =      81,920 B
    float* cs  = (float*)(ws + 11091968);          // 20480*4     =      81,920 B

    prep_f<<<NSPK, 256, 0, stream>>>(E, A, Bc, dg, cs, out);
    gemm_fin<<<256, 256, 0, stream>>>(A, Bc, wp, bp, dg, cs, out);
}

// Round 4
// 105.210 us; speedup vs baseline: 1.0252x; 1.0252x over previous
//
#include <hip/hip_runtime.h>
#include <hip/hip_bf16.h>

typedef unsigned short u16;
typedef unsigned int u32;
typedef unsigned char u8;
typedef int i32x8 __attribute__((ext_vector_type(8)));
typedef float f32x4 __attribute__((ext_vector_type(4)));

#define NSPK 1024
#define NUTT 20
#define DEMB 512
#define NROW (NSPK * NUTT)   // 20480

// pack 8 fp32 -> 8 fp8 e4m3 bytes (HW cvt, gfx950 OCP format — same format MFMA eats)
__device__ __forceinline__ uint2 pk_fp8x8(float a, float b, float c, float d,
                                          float e, float f, float g, float h) {
    int lo = __builtin_amdgcn_cvt_pk_fp8_f32(a, b, 0, 0);
    lo = __builtin_amdgcn_cvt_pk_fp8_f32(c, d, lo, 1);
    int hi = __builtin_amdgcn_cvt_pk_fp8_f32(e, f, 0, 0);
    hi = __builtin_amdgcn_cvt_pk_fp8_f32(g, h, hi, 1);
    return make_uint2((u32)lo, (u32)hi);
}

// ---------------------------------------------------------------------------
// Fused prep (R6-validated, unchanged).
// ---------------------------------------------------------------------------
__global__ __launch_bounds__(256) void prep_f(const float* __restrict__ E,
                                              u8* __restrict__ A,
                                              u8* __restrict__ Bc,
                                              float* __restrict__ diag,
                                              float* __restrict__ csd,
                                              float* __restrict__ out) {
    __shared__ float sbuf[4][DEMB];
    const int t = threadIdx.x, lane = t & 63, wv = t >> 6;
    const int n = blockIdx.x;
    const float* Eb = E + (size_t)n * (NUTT * DEMB) + (size_t)(wv * 5) * DEMB + lane * 8;

    float4 e0[5], e1[5];
    float4 p0 = {0, 0, 0, 0}, p1 = {0, 0, 0, 0};
#pragma unroll
    for (int i = 0; i < 5; ++i) {
        e0[i] = *(const float4*)(Eb + (size_t)i * DEMB);
        e1[i] = *(const float4*)(Eb + (size_t)i * DEMB + 4);
        p0.x += e0[i].x; p0.y += e0[i].y; p0.z += e0[i].z; p0.w += e0[i].w;
        p1.x += e1[i].x; p1.y += e1[i].y; p1.z += e1[i].z; p1.w += e1[i].w;
    }
    *(float4*)(&sbuf[wv][lane * 8])     = p0;
    *(float4*)(&sbuf[wv][lane * 8 + 4]) = p1;
    __syncthreads();

    float4 s0 = {0, 0, 0, 0}, s1 = {0, 0, 0, 0};
#pragma unroll
    for (int k = 0; k < 4; ++k) {
        float4 a = *(const float4*)(&sbuf[k][lane * 8]);
        float4 b = *(const float4*)(&sbuf[k][lane * 8 + 4]);
        s0.x += a.x; s0.y += a.y; s0.z += a.z; s0.w += a.w;
        s1.x += b.x; s1.y += b.y; s1.z += b.z; s1.w += b.w;
    }

    float ls = s0.x*s0.x + s0.y*s0.y + s0.z*s0.z + s0.w*s0.w
             + s1.x*s1.x + s1.y*s1.y + s1.z*s1.z + s1.w*s1.w;
#pragma unroll
    for (int o = 32; o; o >>= 1) ls += __shfl_xor(ls, o);
    const float ss = ls;                                       // ||s||^2
    const float rc = 1.0f / fmaxf(sqrtf(ss) * 0.05f, 1e-8f);   // 1/max(||c||,eps)
    const float g  = rc * 0.05f;                               // rc/20

    ((uint2*)(Bc + (size_t)n * DEMB))[lane] =
        pk_fp8x8(s0.x * g, s0.y * g, s0.z * g, s0.w * g,
                 s1.x * g, s1.y * g, s1.z * g, s1.w * g);

#pragma unroll
    for (int i = 0; i < 5; ++i) {
        float ee = e0[i].x*e0[i].x + e0[i].y*e0[i].y + e0[i].z*e0[i].z + e0[i].w*e0[i].w
                 + e1[i].x*e1[i].x + e1[i].y*e1[i].y + e1[i].z*e1[i].z + e1[i].w*e1[i].w;
        float es = e0[i].x*s0.x + e0[i].y*s0.y + e0[i].z*s0.z + e0[i].w*s0.w
                 + e1[i].x*s1.x + e1[i].y*s1.y + e1[i].z*s1.z + e1[i].w*s1.w;
#pragma unroll
        for (int o = 32; o; o >>= 1) { ee += __shfl_xor(ee, o); es += __shfl_xor(es, o); }

        const float rne = 1.0f / fmaxf(sqrtf(ee), 1e-8f);
        const float pxx = ss - 2.f * es + ee;                  // ||s-e||^2
        const float dg  = (es - ee) * rne / fmaxf(sqrtf(pxx), 1.9e-7f);

        const int r = n * NUTT + wv * 5 + i;
        ((uint2*)(A + (size_t)r * DEMB))[lane] =
            pk_fp8x8(e0[i].x * rne, e0[i].y * rne, e0[i].z * rne, e0[i].w * rne,
                     e1[i].x * rne, e1[i].y * rne, e1[i].z * rne, e1[i].w * rne);
        if (lane == 0) {
            diag[r] = dg;
            csd[r]  = es * g * rne;
        }
    }

    if (n == 0 && t == 0) out[0] = 0.f;
}

// ---------------------------------------------------------------------------
// R11: barrier-free fused GEMM+finalize. Grid 256 = 1 block/CU. Block owns
// 80 rows x 1024 cols; A held in registers (R10-validated path).
// NEW: each wave owns its own 256 cols + its own 2x4KB LDS double buffer ->
// ZERO s_barriers in the 32-stage K-loop (per-wave vmcnt/lgkmcnt only; the
// R10 lockstep version paid ~64 barriers + full sched-fence convoys).
// NEW: B-fragments for stage s+1 are ds_read-prefetched BEFORE stage s's 10
// MFMAs -> ~120cy LDS latency hidden under ~350cy of MFMA.
// Wait discipline per wave: stage s issues gload(s+2) after lgkm-draining
// its reads of that buffer; vmcnt(4) proves stage s+1 landed before its
// frag prefetch (vmcnt(0) at s=30 tail). R5 lesson: no __threadfence.
// ---------------------------------------------------------------------------
__device__ __forceinline__ void async_copy16(const void* g, void* l) {
    __builtin_amdgcn_global_load_lds(
        (const __attribute__((address_space(1))) void*)g,
        (__attribute__((address_space(3))) void*)l, 16, 0, 0);
}

__global__ __launch_bounds__(256, 1) void gemm_fin(const u8* __restrict__ A,
                                                   const u8* __restrict__ Bc,
                                                   const float* __restrict__ wp,
                                                   const float* __restrict__ bp,
                                                   const float* __restrict__ diag,
                                                   const float* __restrict__ csd,
                                                   float* __restrict__ out) {
    __shared__ u8 As[80 * DEMB];        // 40 KB, staged once
    __shared__ u8 Bls[4][2][4096];      // per-wave double buffer, 32 KB total
    __shared__ float red[4][80];
    __shared__ float s_red[4];
    const int t = threadIdx.x, lane = t & 63, wv = t >> 6;
    const int ml = lane & 15, q = lane >> 4;
    const int blk = blockIdx.x;         // rows 80*blk .. 80*blk+79
    const u8* Ag = A + (size_t)blk * 80 * DEMB;

    const float w = *wp, bb = *bp;

    // ---- A staging: 10 gload_lds/wave; row r=c>>5, slot sl=c&31 holds
    // logical k-slot sl^(r&31) (XOR swizzle; R10-validated roundtrip). ----
#pragma unroll
    for (int jj = 0; jj < 10; ++jj) {
        const int c = t + 256 * jj;
        const int r = c >> 5, sl = c & 31;
        async_copy16(Ag + (size_t)r * DEMB + ((sl ^ (r & 31)) << 4),
                     As + t * 16 + jj * 4096);
    }

    // ---- per-wave B staging geometry: wave covers cols C0..C0+255 as 8
    // sub-tiles of 32 cols x 4 k-steps of 128 B = 32 stages of 4 KB. ----
    const int C0 = wv * 256;
    int rj[4], kg16[4];
#pragma unroll
    for (int j = 0; j < 4; ++j) {
        const int c = lane + 64 * j;
        rj[j] = c >> 3;                       // local col 0..31
        kg16[j] = ((c & 7) ^ (rj[j] & 7)) << 4;   // swizzled 16B k-slot
    }

#define STAGEB(U, KT, PAR)                                                    \
    {                                                                         \
        _Pragma("unroll")                                                     \
        for (int j = 0; j < 4; ++j)                                           \
            async_copy16(Bc + (size_t)(C0 + (U) * 32 + rj[j]) * DEMB +        \
                             (KT) * 128 + kg16[j],                            \
                         &Bls[wv][PAR][j * 1024 + lane * 16]);                \
    }

    STAGEB(0, 0, 0);                     // stage 0
    STAGEB(0, 1, 1);                     // stage 1; outstanding: 10(A)+8(B)
    asm volatile("s_waitcnt vmcnt(8)" ::: "memory");   // A landed (10 oldest)
    __builtin_amdgcn_sched_barrier(0);
    __builtin_amdgcn_s_barrier();        // the ONLY cross-wave barrier pre-loop
    __builtin_amdgcn_sched_barrier(0);

    // ---- A-tile -> registers (R10-validated). frag m: rows m*16+ml; lane q
    // covers k-slots {kt*8+2q, +1}. ----
    i32x8 a[5][4];
#pragma unroll
    for (int m = 0; m < 5; ++m) {
        const int r = m * 16 + ml;
#pragma unroll
        for (int kt = 0; kt < 4; ++kt) {
            const int sl0 = (kt * 8 + 2 * q)     ^ (r & 31);
            const int sl1 = (kt * 8 + 2 * q + 1) ^ (r & 31);
            uint4 x = *(const uint4*)(As + r * DEMB + (sl0 << 4));
            uint4 y = *(const uint4*)(As + r * DEMB + (sl1 << 4));
            a[m][kt] = (i32x8){(int)x.x, (int)x.y, (int)x.z, (int)x.w,
                               (int)y.x, (int)y.y, (int)y.z, (int)y.w};
        }
    }

    f32x4 acc[5][2], rowpart[5];
#pragma unroll
    for (int m = 0; m < 5; ++m) {
        acc[m][0] = (f32x4){0.f, 0.f, 0.f, 0.f};
        acc[m][1] = (f32x4){0.f, 0.f, 0.f, 0.f};
        rowpart[m] = (f32x4){0.f, 0.f, 0.f, 0.f};
    }

    // B fragment offsets within a 4 KB stage buffer: local col cc = nf*16+ml,
    // lane q reads logical slots 2q,2q+1 of cc's 128 B (XOR-swizzle inverse).
    int bo0[2], bo1[2];
#pragma unroll
    for (int nf = 0; nf < 2; ++nf) {
        const int cc = nf * 16 + ml;
        bo0[nf] = cc * 128 + (((2 * q)     ^ (cc & 7)) << 4);
        bo1[nf] = cc * 128 + (((2 * q + 1) ^ (cc & 7)) << 4);
    }

    i32x8 bf[2][2];                      // [stage parity][nf]
#define LOADBF(PAR)                                                           \
    {                                                                         \
        _Pragma("unroll")                                                     \
        for (int nf = 0; nf < 2; ++nf) {                                      \
            uint4 x = *(const uint4*)(&Bls[wv][PAR][bo0[nf]]);                \
            uint4 y = *(const uint4*)(&Bls[wv][PAR][bo1[nf]]);                \
            bf[PAR][nf] = (i32x8){(int)x.x, (int)x.y, (int)x.z, (int)x.w,     \
                                  (int)y.x, (int)y.y, (int)y.z, (int)y.w};    \
        }                                                                     \
    }

    // prologue frag prefetch: stage 0 landed when vmcnt<=4 (B0 older than B1)
    asm volatile("s_waitcnt vmcnt(4)" ::: "memory");
    __builtin_amdgcn_sched_barrier(0);
    LOADBF(0);

    // ---- barrier-free main loop: 32 stages, fully unrolled ----
#pragma unroll
    for (int u = 0; u < 8; ++u) {
#pragma unroll
        for (int kt = 0; kt < 4; ++kt) {
            const int s = u * 4 + kt, par = s & 1;
            // a) drain this wave's ds_reads of buffer `par` (done last stage)
            asm volatile("s_waitcnt lgkmcnt(0)" ::: "memory");
            __builtin_amdgcn_sched_barrier(0);
            // b) refill buffer `par` with stage s+2 (WAR-safe: reads drained)
            if (s + 2 < 32) {
                const int s2 = s + 2;
                STAGEB(s2 >> 2, s2 & 3, par);
            }
            __builtin_amdgcn_sched_barrier(0);
            // c) stage s+1 landed? (outstanding: s+1, s+2 -> wait 4)
            if (s == 30)      { asm volatile("s_waitcnt vmcnt(0)" ::: "memory"); }
            else if (s < 30)  { asm volatile("s_waitcnt vmcnt(4)" ::: "memory"); }
            __builtin_amdgcn_sched_barrier(0);
            // d) prefetch stage s+1 frags; latency hidden under e)'s MFMAs
            if (s < 31) LOADBF(par ^ 1);
            // e) 10 MFMAs with the in-register frags of stage s
#pragma unroll
            for (int m = 0; m < 5; ++m)
#pragma unroll
                for (int nf = 0; nf < 2; ++nf)
                    acc[m][nf] = __builtin_amdgcn_mfma_scale_f32_16x16x128_f8f6f4(
                        a[m][kt], bf[par][nf], acc[m][nf], 0, 0,
                        0, 0x7F7F7F7F, 0, 0x7F7F7F7F);   // unit scales
            // f) per-subtile epilogue: fold exp row-sums, free acc (VALU only)
            if (kt == 3) {
#pragma unroll
                for (int m = 0; m < 5; ++m) {
#pragma unroll
                    for (int r = 0; r < 4; ++r)
                        rowpart[m][r] += __expf(fmaf(w, acc[m][0][r] + 1e-6f, bb))
                                       + __expf(fmaf(w, acc[m][1][r] + 1e-6f, bb));
                    acc[m][0] = (f32x4){0.f, 0.f, 0.f, 0.f};
                    acc[m][1] = (f32x4){0.f, 0.f, 0.f, 0.f};
                }
            }
        }
    }
#undef STAGEB
#undef LOADBF

    // ---- final: 16-lane reduce of rowpart, cross-wave via LDS ----
#pragma unroll
    for (int m = 0; m < 5; ++m)
#pragma unroll
        for (int o = 1; o < 16; o <<= 1) {
            rowpart[m][0] += __shfl_xor(rowpart[m][0], o);
            rowpart[m][1] += __shfl_xor(rowpart[m][1], o);
            rowpart[m][2] += __shfl_xor(rowpart[m][2], o);
            rowpart[m][3] += __shfl_xor(rowpart[m][3], o);
        }
    if (ml == 0) {
#pragma unroll
        for (int m = 0; m < 5; ++m)
#pragma unroll
            for (int r = 0; r < 4; ++r)
                red[wv][m * 16 + q * 4 + r] = rowpart[m][r];   // C row = q*4+reg
    }
    __syncthreads();

    float term = 0.f;
    if (t < 80) {
        const float rsum = red[0][t] + red[1][t] + red[2][t] + red[3][t];
        const int row = blk * 80 + t;
        const float pos = fmaf(w, diag[row] + 1e-6f, bb);
        const float S = rsum - __expf(fmaf(w, csd[row] + 1e-6f, bb)) + __expf(pos);
        term = __logf(S + 1e-6f) - pos;
    }
#pragma unroll
    for (int o = 32; o; o >>= 1) term += __shfl_xor(term, o);
    if (lane == 0) s_red[wv] = term;
    __syncthreads();
    if (t == 0) atomicAdd(out, s_red[0] + s_red[1] + s_red[2] + s_red[3]);
}

extern "C" void kernel_launch(void* const* d_in, const int* in_sizes, int n_in,
                              void* d_out, int out_size, void* d_ws, size_t ws_size,
                              hipStream_t stream) {
    const float* E = (const float*)d_in[0];
    const float* wp = (const float*)d_in[1];
    const float* bp = (const float*)d_in[2];
    float* out = (float*)d_out;

    char* ws = (char*)d_ws;
    u8* A      = (u8*)(ws);                        // 20480*512   = 10,485,760 B
    u8* Bc     = (u8*)(ws + 10485760);             //  1024*512   =     524,288 B
    float* dg  = (float*)(ws + 11010048);          // 20480*4     =      81,920 B
    float* cs  = (float*)(ws + 11091968);          // 20480*4     =      81,920 B

    prep_f<<<NSPK, 256, 0, stream>>>(E, A, Bc, dg, cs, out);
    gemm_fin<<<256, 256, 0, stream>>>(A, Bc, wp, bp, dg, cs, out);
}